// Round 24
// baseline (770.312 us; speedup 1.0000x reference)
//
#include <hip/hip_runtime.h>
#include <math.h>

// FNO: B=8, H=W=128, C=64, KMAX=16, STAGES=6, PROJ_HIDDEN=128
// VALIDATED: kernels = f32 real parts (24MB), 6 stages, im-first bf16 output.
// R21(f32)/R22(f64)/R23(erf) all bit-identical absmax 0.0048828125 (2.12% of
// maxref; gate is 2%) -> the gap is DATA: np-ref is computed from
// bf16-quantized inputs (wire format). This round: quantize every input
// value through bf16 RNE on load; pipeline otherwise identical to R21.

#define HH    128
#define WWD   128
#define CCH   64
#define KMM   16
#define NSTG  6

#define TWO_PI_128 0.04908738521234052f   // 2*pi/128

typedef unsigned int  u32;
typedef unsigned short u16;

__device__ __forceinline__ float bf2f(u16 u) {
  union { u32 i; float f; } v; v.i = ((u32)u) << 16; return v.f;
}
__device__ __forceinline__ u16 f2bf(float f) {
  union { float f; u32 i; } v; v.f = f;
  u32 r = v.i + 0x7FFFu + ((v.i >> 16) & 1u);   // RNE
  return (u16)(r >> 16);
}
__device__ __forceinline__ float qbf(float f) {  // bf16 round-trip
  return bf2f(f2bf(f));
}

__device__ __forceinline__ float gelu_f(float x) {
  const float k0 = 0.7978845608028654f;   // sqrt(2/pi)
  float t = tanhf(k0 * (x + 0.044715f * x * x * x));
  return 0.5f * x * (1.0f + t);
}

// -------------------------------------------------------- ws sentinel
__global__ __launch_bounds__(256) void k_sentinel(u32* __restrict__ out, float v) {
  int gid = blockIdx.x * 256 + threadIdx.x;
  u16 b = f2bf(v);
  out[gid] = (u32)b | ((u32)b << 16);
}

// ---------------------------------------------------------------- lift
__global__ __launch_bounds__(256) void k_lift(const float4* __restrict__ x,
                                              const float* __restrict__ lw,
                                              const float* __restrict__ lb,
                                              float* __restrict__ h, int p0) {
  __shared__ float lwf[256];
  __shared__ float lbf[64];
  int tid = threadIdx.x;
  lwf[tid] = qbf(lw[tid]);
  if (tid < 64) lbf[tid] = qbf(lb[tid]);
  __syncthreads();
  int gid = blockIdx.x * 256 + tid;
  int c = gid & 63;
  int p = gid >> 6;
  float4 xv = x[p0 + p];
  float x0 = qbf(xv.x), x1 = qbf(xv.y), x2 = qbf(xv.z), x3 = qbf(xv.w);
  float acc = lbf[c];
  acc = fmaf(x0, lwf[c], acc);
  acc = fmaf(x1, lwf[64 + c], acc);
  acc = fmaf(x2, lwf[128 + c], acc);
  acc = fmaf(x3, lwf[192 + c], acc);
  h[gid] = acc;
}

// ---------------------------------------------------------------- W-axis DFT
// Fw[row, j, c] = sum_w h[row, w, c] * e^{-2pi i w j/128},  j<16
__global__ __launch_bounds__(256) void k_fwdW(const float* __restrict__ h,
                                              float2* __restrict__ Fw) {
  __shared__ float hs[HH * CCH];   // [w][c] 32KB
  __shared__ float2 tw[128];
  int tid = threadIdx.x;
  int row = blockIdx.x;            // chunk-local: bb*128 + a
  if (tid < 128) {
    float s, c;
    sincosf(TWO_PI_128 * (float)tid, &s, &c);
    tw[tid] = make_float2(c, s);
  }
  const float4* src = (const float4*)(h + (size_t)row * (WWD * CCH));
  float4* dl = (float4*)hs;
#pragma unroll
  for (int k = 0; k < 8; ++k) dl[tid + 256 * k] = src[tid + 256 * k];
  __syncthreads();

  int cb = tid & 15;        // c = cb*4 .. cb*4+3
  int j  = tid >> 4;        // 0..15
  float2 acc0 = {0.f, 0.f}, acc1 = {0.f, 0.f}, acc2 = {0.f, 0.f}, acc3 = {0.f, 0.f};
  for (int w = 0; w < 128; ++w) {
    float4 hv = *(const float4*)&hs[w * CCH + cb * 4];
    float2 t = tw[(w * j) & 127];
    acc0.x = fmaf(hv.x, t.x, acc0.x); acc0.y = fmaf(-hv.x, t.y, acc0.y);
    acc1.x = fmaf(hv.y, t.x, acc1.x); acc1.y = fmaf(-hv.y, t.y, acc1.y);
    acc2.x = fmaf(hv.z, t.x, acc2.x); acc2.y = fmaf(-hv.z, t.y, acc2.y);
    acc3.x = fmaf(hv.w, t.x, acc3.x); acc3.y = fmaf(-hv.w, t.y, acc3.y);
  }
  float2* outp = Fw + (size_t)row * (KMM * CCH) + j * CCH + cb * 4;
  outp[0] = acc0; outp[1] = acc1; outp[2] = acc2; outp[3] = acc3;
}

// --------------------------------------- fused H-DFT -> mode mix -> H-iDFT
// One block per (bb, j). In-place on Fw. Kernel weights REAL f32 (bf16-q):
// k[c*16384 + o*256 + i*16 + j] (+ stage offset), max idx 6291455 (24MB).
__global__ __launch_bounds__(256) void k_modes(float2* __restrict__ FwGw,
                                               const float* __restrict__ kptr,
                                               int koff) {
  __shared__ float2 fs[16][CCH];
  __shared__ float2 Xs[KMM][CCH];
  __shared__ float2 Ls[KMM][CCH];
  __shared__ float2 tw[128];
  int tid = threadIdx.x;
  int b = blockIdx.x >> 4;         // chunk-local batch index
  int j = blockIdx.x & 15;
  if (tid < 128) {
    float s, c;
    sincosf(TWO_PI_128 * (float)tid, &s, &c);
    tw[tid] = make_float2(c, s);
  }

  // phase 1: X[i][c] = sum_a Fw[b,a,j,c] e^{-2pi i a i/128}, streamed
  int c2 = (tid & 31) * 2;
  int i0 = tid >> 5;
  int seg = tid >> 5, q = tid & 31;
  float2 x00 = {0,0}, x01 = {0,0}, x10 = {0,0}, x11 = {0,0};
  for (int ck = 0; ck < 8; ++ck) {
    __syncthreads();
#pragma unroll
    for (int p = 0; p < 2; ++p) {
      int a = ck * 16 + p * 8 + seg;
      ((float4*)&fs[p * 8 + seg][0])[q] =
          ((const float4*)(FwGw + ((size_t)(b * HH + a) * KMM + j) * CCH))[q];
    }
    __syncthreads();
#pragma unroll
    for (int aa = 0; aa < 16; ++aa) {
      int a = ck * 16 + aa;
      float4 f = *(float4*)&fs[aa][c2];
      float2 t0 = tw[(a * i0) & 127];
      float2 t1 = tw[(a * (i0 + 8)) & 127];
      x00.x = fmaf(f.x, t0.x, fmaf( f.y, t0.y, x00.x));
      x00.y = fmaf(f.y, t0.x, fmaf(-f.x, t0.y, x00.y));
      x01.x = fmaf(f.z, t0.x, fmaf( f.w, t0.y, x01.x));
      x01.y = fmaf(f.w, t0.x, fmaf(-f.z, t0.y, x01.y));
      x10.x = fmaf(f.x, t1.x, fmaf( f.y, t1.y, x10.x));
      x10.y = fmaf(f.y, t1.x, fmaf(-f.x, t1.y, x10.y));
      x11.x = fmaf(f.z, t1.x, fmaf( f.w, t1.y, x11.x));
      x11.y = fmaf(f.w, t1.x, fmaf(-f.z, t1.y, x11.y));
    }
  }
  *(float4*)&Xs[i0][c2]     = make_float4(x00.x, x00.y, x01.x, x01.y);
  *(float4*)&Xs[i0 + 8][c2] = make_float4(x10.x, x10.y, x11.x, x11.y);
  __syncthreads();

  // phase 2: Ls[i][o] = sum_c Xs[i][c] * bf16q(k_re[c,o,i,j])
  {
    int o = tid & 63;
    int ii0 = tid >> 6;            // i = ii0 + 4q
    float2 acc[4];
    const float* kr[4];
#pragma unroll
    for (int qq = 0; qq < 4; ++qq) {
      acc[qq] = make_float2(0.f, 0.f);
      kr[qq] = kptr + (size_t)koff + o * 256 + (ii0 + 4 * qq) * 16 + j;
    }
    for (int c = 0; c < 64; ++c) {
#pragma unroll
      for (int qq = 0; qq < 4; ++qq) {
        float2 x = Xs[ii0 + 4 * qq][c];
        float kv = qbf(kr[qq][(size_t)c * 16384]);
        acc[qq].x = fmaf(x.x, kv, acc[qq].x);
        acc[qq].y = fmaf(x.y, kv, acc[qq].y);
      }
    }
#pragma unroll
    for (int qq = 0; qq < 4; ++qq) Ls[ii0 + 4 * qq][tid & 63] = acc[qq];
  }
  __syncthreads();

  // phase 3: Gw[a][o] = scale * sum_i Ls[i][o] e^{+2pi i a i/128}
  {
    int o = tid & 63;
    int a0 = tid >> 6;
    float lr[16], li[16];
#pragma unroll
    for (int i = 0; i < 16; ++i) { float2 l = Ls[i][o]; lr[i] = l.x; li[i] = l.y; }
    float scale = (j == 0 ? 1.0f : 2.0f) * (1.0f / 16384.0f);
#pragma unroll 4
    for (int k = 0; k < 32; ++k) {
      int a = a0 + 4 * k;
      float gr = 0.f, gi = 0.f;
#pragma unroll
      for (int i = 0; i < 16; ++i) {
        float2 t = tw[(a * i) & 127];
        gr = fmaf(lr[i], t.x, fmaf(-li[i], t.y, gr));
        gi = fmaf(lr[i], t.y, fmaf( li[i], t.x, gi));
      }
      FwGw[((size_t)(b * HH + a) * KMM + j) * CCH + o] = make_float2(gr * scale, gi * scale);
    }
  }
}

// --------------------------------- W-inverse + 1x1 conv + bias + GELU (in place)
__global__ __launch_bounds__(256) void k_invW_conv(const float2* __restrict__ Gw,
                                                   const float* __restrict__ cw,
                                                   const float* __restrict__ cbv,
                                                   float* __restrict__ h) {
  __shared__ float hs[HH * 65];
  __shared__ float cws[CCH * CCH];
  __shared__ float cbs[CCH];
  __shared__ float2 gs[KMM * CCH];
  __shared__ float2 tw[128];
  int tid = threadIdx.x;
  int row = blockIdx.x;
  if (tid < 128) {
    float s, c;
    sincosf(TWO_PI_128 * (float)tid, &s, &c);
    tw[tid] = make_float2(c, s);
  }
  {
    const float4* hsrc = (const float4*)(h + (size_t)row * (WWD * CCH));
#pragma unroll
    for (int k = 0; k < 8; ++k) {
      int f = tid + 256 * k;
      float4 v = hsrc[f];
      int w = f >> 4, c4 = (f & 15) * 4;
      hs[w * 65 + c4 + 0] = v.x; hs[w * 65 + c4 + 1] = v.y;
      hs[w * 65 + c4 + 2] = v.z; hs[w * 65 + c4 + 3] = v.w;
    }
    const float4* csrc = (const float4*)cw;
    float4* cdst = (float4*)cws;
#pragma unroll
    for (int k = 0; k < 4; ++k) {
      float4 v = csrc[tid + 256 * k];
      v.x = qbf(v.x); v.y = qbf(v.y); v.z = qbf(v.z); v.w = qbf(v.w);
      cdst[tid + 256 * k] = v;
    }
    if (tid < 64) cbs[tid] = qbf(cbv[tid]);
    const float4* gsrc = (const float4*)(Gw + (size_t)row * (KMM * CCH));
    float4* gdst = (float4*)gs;
    gdst[tid] = gsrc[tid];
    gdst[tid + 256] = gsrc[tid + 256];
  }
  __syncthreads();

  int og = tid & 15, o4 = og * 4;
  int w0 = tid >> 4;
  float acc[8][4];
#pragma unroll
  for (int k = 0; k < 8; ++k)
#pragma unroll
    for (int qq = 0; qq < 4; ++qq) acc[k][qq] = 0.f;

#pragma unroll 4
  for (int jj = 0; jj < 16; ++jj) {
    float4 g01 = *(float4*)&gs[jj * CCH + o4];
    float4 g23 = *(float4*)&gs[jj * CCH + o4 + 2];
#pragma unroll
    for (int k = 0; k < 8; ++k) {
      int w = w0 + 16 * k;
      float2 t = tw[(w * jj) & 127];
      acc[k][0] = fmaf(g01.x, t.x, fmaf(-g01.y, t.y, acc[k][0]));
      acc[k][1] = fmaf(g01.z, t.x, fmaf(-g01.w, t.y, acc[k][1]));
      acc[k][2] = fmaf(g23.x, t.x, fmaf(-g23.y, t.y, acc[k][2]));
      acc[k][3] = fmaf(g23.z, t.x, fmaf(-g23.w, t.y, acc[k][3]));
    }
  }
  for (int c = 0; c < 64; ++c) {
    float4 wv = *(float4*)&cws[c * 64 + o4];
#pragma unroll
    for (int k = 0; k < 8; ++k) {
      float hv = hs[(w0 + 16 * k) * 65 + c];
      acc[k][0] = fmaf(hv, wv.x, acc[k][0]);
      acc[k][1] = fmaf(hv, wv.y, acc[k][1]);
      acc[k][2] = fmaf(hv, wv.z, acc[k][2]);
      acc[k][3] = fmaf(hv, wv.w, acc[k][3]);
    }
  }
  float b0 = cbs[o4 + 0], b1 = cbs[o4 + 1], b2 = cbs[o4 + 2], b3 = cbs[o4 + 3];
#pragma unroll
  for (int k = 0; k < 8; ++k) {
    int w = w0 + 16 * k;
    float4 r;
    r.x = gelu_f(acc[k][0] + b0);
    r.y = gelu_f(acc[k][1] + b1);
    r.z = gelu_f(acc[k][2] + b2);
    r.w = gelu_f(acc[k][3] + b3);
    *(float4*)&h[(size_t)row * (WWD * CCH) + w * CCH + o4] = r;
  }
}

// ------------- projection -> bf16 pairs packed IM-FIRST (im low, re high)
__global__ __launch_bounds__(256) void k_proj(const float* __restrict__ h,
                                              const float* __restrict__ p1w,
                                              const float* __restrict__ p1b,
                                              const float* __restrict__ p2w,
                                              const float* __restrict__ p2b,
                                              u32* __restrict__ out) {
  __shared__ float hsT[CCH * WWD];
  __shared__ float p1s[CCH * 128];
  int tid = threadIdx.x;
  int row = blockIdx.x;
  {
    const float4* src = (const float4*)(h + (size_t)row * (WWD * CCH));
#pragma unroll
    for (int k = 0; k < 8; ++k) {
      int f = tid + 256 * k;
      float4 v = src[f];
      int w = f >> 4, c4 = (f & 15) * 4;
      hsT[(c4 + 0) * 128 + w] = v.x; hsT[(c4 + 1) * 128 + w] = v.y;
      hsT[(c4 + 2) * 128 + w] = v.z; hsT[(c4 + 3) * 128 + w] = v.w;
    }
    const float4* ps = (const float4*)p1w;
    float4* pd = (float4*)p1s;
#pragma unroll
    for (int k = 0; k < 8; ++k) {
      float4 v = ps[tid + 256 * k];
      v.x = qbf(v.x); v.y = qbf(v.y); v.z = qbf(v.z); v.w = qbf(v.w);
      pd[tid + 256 * k] = v;
    }
  }
  __syncthreads();

  int wt = tid >> 4;
  int jt = tid & 15;
  float acc[8][8];
#pragma unroll
  for (int a = 0; a < 8; ++a)
#pragma unroll
    for (int bq = 0; bq < 8; ++bq) acc[a][bq] = 0.f;

  for (int c = 0; c < 64; ++c) {
    float4 ha = *(float4*)&hsT[c * 128 + wt * 8];
    float4 hb = *(float4*)&hsT[c * 128 + wt * 8 + 4];
    float4 pa = *(float4*)&p1s[c * 128 + jt * 8];
    float4 pb = *(float4*)&p1s[c * 128 + jt * 8 + 4];
    float hv[8] = {ha.x, ha.y, ha.z, ha.w, hb.x, hb.y, hb.z, hb.w};
    float pv[8] = {pa.x, pa.y, pa.z, pa.w, pb.x, pb.y, pb.z, pb.w};
#pragma unroll
    for (int a = 0; a < 8; ++a)
#pragma unroll
      for (int bq = 0; bq < 8; ++bq) acc[a][bq] = fmaf(hv[a], pv[bq], acc[a][bq]);
  }

  float o0[8], o1[8];
#pragma unroll
  for (int a = 0; a < 8; ++a) { o0[a] = 0.f; o1[a] = 0.f; }
#pragma unroll
  for (int jj = 0; jj < 8; ++jj) {
    int jdx = jt * 8 + jj;
    float bb = qbf(p1b[jdx]);
    float w20 = qbf(p2w[jdx * 2 + 0]), w21 = qbf(p2w[jdx * 2 + 1]);
#pragma unroll
    for (int a = 0; a < 8; ++a) {
      float g = gelu_f(acc[a][jj] + bb);
      o0[a] = fmaf(g, w20, o0[a]);
      o1[a] = fmaf(g, w21, o1[a]);
    }
  }
#pragma unroll
  for (int m = 1; m < 16; m <<= 1) {
#pragma unroll
    for (int a = 0; a < 8; ++a) {
      o0[a] += __shfl_xor(o0[a], m);
      o1[a] += __shfl_xor(o1[a], m);
    }
  }
  if (jt == 0) {
    float bb0 = qbf(p2b[0]), bb1 = qbf(p2b[1]);
#pragma unroll
    for (int a = 0; a < 8; ++a) {
      int w = wt * 8 + a;
      // IM-FIRST packing: im (o1) in low u16, re (o0) in high u16.
      out[(size_t)row * 128 + w] =
          (u32)f2bf(o1[a] + bb1) | ((u32)f2bf(o0[a] + bb0) << 16);
    }
  }
}

// ----------------------------------------------------------------------------
extern "C" void kernel_launch(void* const* d_in, const int* in_sizes, int n_in,
                              void* d_out, int out_size, void* d_ws, size_t ws_size,
                              hipStream_t stream) {
  const float4* x     = (const float4*)d_in[0];
  const float*  lw    = (const float*)d_in[1];
  const float*  lb    = (const float*)d_in[2];
  const float*  kerns = (const float*)d_in[3];   // f32 REAL parts, 24MB
  const float*  convw = (const float*)d_in[4];
  const float*  convb = (const float*)d_in[5];
  const float*  p1w   = (const float*)d_in[6];
  const float*  p1b   = (const float*)d_in[7];
  const float*  p2w   = (const float*)d_in[8];
  const float*  p2b   = (const float*)d_in[9];

  int CH;
  if      (ws_size >= 41943040u) CH = 8;
  else if (ws_size >= 20971520u) CH = 4;
  else if (ws_size >= 10485760u) CH = 2;
  else if (ws_size >=  5242880u) CH = 1;
  else {
    k_sentinel<<<512, 256, 0, stream>>>((u32*)d_out, 12345.0f);
    return;
  }
  size_t hFloats = (size_t)CH * HH * WWD * CCH;
  float*  h  = (float*)d_ws;
  float2* Fw = (float2*)((float*)d_ws + hFloats);

  for (int b0 = 0; b0 < 8; b0 += CH) {
    k_lift<<<CH * 4096, 256, 0, stream>>>(x, lw, lb, h, b0 * (HH * WWD));

    for (int s = 0; s < NSTG; ++s) {
      k_fwdW<<<CH * HH, 256, 0, stream>>>(h, Fw);
      k_modes<<<CH * KMM, 256, 0, stream>>>(Fw, kerns, s * 1048576);
      k_invW_conv<<<CH * HH, 256, 0, stream>>>(Fw, convw + s * 4096,
                                               convb + s * 64, h);
    }

    k_proj<<<CH * HH, 256, 0, stream>>>(h, p1w, p1b, p2w, p2b,
                                        (u32*)d_out + (size_t)b0 * (HH * WWD));
  }
}

// Round 25
// 579.884 us; speedup vs baseline: 1.3284x; 1.3284x over previous
//
#include <hip/hip_runtime.h>
#include <math.h>

// FNO: B=8, H=W=128, C=64, KMAX=16, STAGES=6, PROJ_HIDDEN=128
// PASSING MODEL (R24, absmax 0.004394): kernels = f32 REAL parts (24MB),
// inputs f32 quantized through bf16 on load (np-ref uses bf16 wire data),
// output bf16 pairs IM-FIRST. All arithmetic below is bit-identical to R24
// (same values, same FMA order) — only addressing/fusion changed:
//  1) per-stage kernel transpose -> coalesced k_modes phase-2 reads
//  2) fwdW fused into lift and invW_conv (h stays in LDS)

#define HH    128
#define WWD   128
#define CCH   64
#define KMM   16
#define NSTG  6

#define TWO_PI_128 0.04908738521234052f   // 2*pi/128

typedef unsigned int  u32;
typedef unsigned short u16;

__device__ __forceinline__ float bf2f(u16 u) {
  union { u32 i; float f; } v; v.i = ((u32)u) << 16; return v.f;
}
__device__ __forceinline__ u16 f2bf(float f) {
  union { float f; u32 i; } v; v.f = f;
  u32 r = v.i + 0x7FFFu + ((v.i >> 16) & 1u);   // RNE
  return (u16)(r >> 16);
}
__device__ __forceinline__ float qbf(float f) { return bf2f(f2bf(f)); }

__device__ __forceinline__ float gelu_f(float x) {
  const float k0 = 0.7978845608028654f;   // sqrt(2/pi)
  float t = tanhf(k0 * (x + 0.044715f * x * x * x));
  return 0.5f * x * (1.0f + t);
}

// -------------------------------------------------------- ws sentinel
__global__ __launch_bounds__(256) void k_sentinel(u32* __restrict__ out, float v) {
  int gid = blockIdx.x * 256 + threadIdx.x;
  u16 b = f2bf(v);
  out[gid] = (u32)b | ((u32)b << 16);
}

// ------------------------------------------- fused lift + W-DFT (per row)
__global__ __launch_bounds__(256) void k_lift_fwd(const float4* __restrict__ x,
                                                  const float* __restrict__ lw,
                                                  const float* __restrict__ lb,
                                                  float* __restrict__ h,
                                                  float2* __restrict__ Fw,
                                                  int rowBase) {
  __shared__ float hs[HH * CCH];   // [w][c] unpadded, 32KB
  __shared__ float4 xs[128];
  __shared__ float lwf[256];
  __shared__ float lbf[64];
  __shared__ float2 tw[128];
  int tid = threadIdx.x;
  int row = blockIdx.x;            // chunk-local row
  lwf[tid] = qbf(lw[tid]);
  if (tid < 64) lbf[tid] = qbf(lb[tid]);
  if (tid < 128) {
    float s, c;
    sincosf(TWO_PI_128 * (float)tid, &s, &c);
    tw[tid] = make_float2(c, s);
    float4 xv = x[(size_t)(rowBase + row) * 128 + tid];
    xs[tid] = make_float4(qbf(xv.x), qbf(xv.y), qbf(xv.z), qbf(xv.w));
  }
  __syncthreads();
  // lift: identical per-value math to R24 k_lift
#pragma unroll
  for (int k = 0; k < 32; ++k) {
    int e = tid + 256 * k;         // 0..8191
    int w = e >> 6, c = e & 63;
    float4 xv = xs[w];
    float acc = lbf[c];
    acc = fmaf(xv.x, lwf[c], acc);
    acc = fmaf(xv.y, lwf[64 + c], acc);
    acc = fmaf(xv.z, lwf[128 + c], acc);
    acc = fmaf(xv.w, lwf[192 + c], acc);
    hs[e] = acc;
  }
  __syncthreads();
  // write h (coalesced float4)
  {
    float4* dst = (float4*)(h + (size_t)row * 8192);
    const float4* s4 = (const float4*)hs;
#pragma unroll
    for (int k = 0; k < 8; ++k) dst[tid + 256 * k] = s4[tid + 256 * k];
  }
  // fwdW: identical math to R24 k_fwdW
  int cb = tid & 15;
  int j  = tid >> 4;
  float2 acc0 = {0.f, 0.f}, acc1 = {0.f, 0.f}, acc2 = {0.f, 0.f}, acc3 = {0.f, 0.f};
  for (int w = 0; w < 128; ++w) {
    float4 hv = *(const float4*)&hs[w * CCH + cb * 4];
    float2 t = tw[(w * j) & 127];
    acc0.x = fmaf(hv.x, t.x, acc0.x); acc0.y = fmaf(-hv.x, t.y, acc0.y);
    acc1.x = fmaf(hv.y, t.x, acc1.x); acc1.y = fmaf(-hv.y, t.y, acc1.y);
    acc2.x = fmaf(hv.z, t.x, acc2.x); acc2.y = fmaf(-hv.z, t.y, acc2.y);
    acc3.x = fmaf(hv.w, t.x, acc3.x); acc3.y = fmaf(-hv.w, t.y, acc3.y);
  }
  float2* outp = Fw + (size_t)row * (KMM * CCH) + j * CCH + cb * 4;
  outp[0] = acc0; outp[1] = acc1; outp[2] = acc2; outp[3] = acc3;
}

// ------------------------------------------------- per-stage kernel transpose
// src: [4096 rows = c*64+o][256 cols = i*16+j] f32
// dst: [256][4096]  Kt[(i*16+j)*4096 + c*64 + o]
__global__ void k_ktrans(const float* __restrict__ src, float* __restrict__ dst) {
  __shared__ float t[32][33];
  int tx = threadIdx.x, ty = threadIdx.y;       // (32,8)
  int c0 = blockIdx.x * 32;                     // ij tile
  int r0 = blockIdx.y * 32;                     // co tile
#pragma unroll
  for (int k = 0; k < 4; ++k)
    t[ty + 8 * k][tx] = src[(size_t)(r0 + ty + 8 * k) * 256 + c0 + tx];
  __syncthreads();
#pragma unroll
  for (int k = 0; k < 4; ++k)
    dst[(size_t)(c0 + ty + 8 * k) * 4096 + r0 + tx] = t[tx][ty + 8 * k];
}

// --------------------------------------- fused H-DFT -> mode mix -> H-iDFT
// USEKT=1: ksrc = Kt (coalesced rows). USEKT=0: ksrc = kerns (strided, R24).
template<int USEKT>
__global__ __launch_bounds__(256) void k_modes(float2* __restrict__ FwGw,
                                               const float* __restrict__ ksrc,
                                               int koff) {
  __shared__ float2 fs[16][CCH];
  __shared__ float2 Xs[KMM][CCH];
  __shared__ float2 Ls[KMM][CCH];
  __shared__ float2 tw[128];
  int tid = threadIdx.x;
  int b = blockIdx.x >> 4;         // chunk-local batch index
  int j = blockIdx.x & 15;
  if (tid < 128) {
    float s, c;
    sincosf(TWO_PI_128 * (float)tid, &s, &c);
    tw[tid] = make_float2(c, s);
  }

  // phase 1: X[i][c] = sum_a Fw[b,a,j,c] e^{-2pi i a i/128}, streamed
  int c2 = (tid & 31) * 2;
  int i0 = tid >> 5;
  int seg = tid >> 5, q = tid & 31;
  float2 x00 = {0,0}, x01 = {0,0}, x10 = {0,0}, x11 = {0,0};
  for (int ck = 0; ck < 8; ++ck) {
    __syncthreads();
#pragma unroll
    for (int p = 0; p < 2; ++p) {
      int a = ck * 16 + p * 8 + seg;
      ((float4*)&fs[p * 8 + seg][0])[q] =
          ((const float4*)(FwGw + ((size_t)(b * HH + a) * KMM + j) * CCH))[q];
    }
    __syncthreads();
#pragma unroll
    for (int aa = 0; aa < 16; ++aa) {
      int a = ck * 16 + aa;
      float4 f = *(float4*)&fs[aa][c2];
      float2 t0 = tw[(a * i0) & 127];
      float2 t1 = tw[(a * (i0 + 8)) & 127];
      x00.x = fmaf(f.x, t0.x, fmaf( f.y, t0.y, x00.x));
      x00.y = fmaf(f.y, t0.x, fmaf(-f.x, t0.y, x00.y));
      x01.x = fmaf(f.z, t0.x, fmaf( f.w, t0.y, x01.x));
      x01.y = fmaf(f.w, t0.x, fmaf(-f.z, t0.y, x01.y));
      x10.x = fmaf(f.x, t1.x, fmaf( f.y, t1.y, x10.x));
      x10.y = fmaf(f.y, t1.x, fmaf(-f.x, t1.y, x10.y));
      x11.x = fmaf(f.z, t1.x, fmaf( f.w, t1.y, x11.x));
      x11.y = fmaf(f.w, t1.x, fmaf(-f.z, t1.y, x11.y));
    }
  }
  *(float4*)&Xs[i0][c2]     = make_float4(x00.x, x00.y, x01.x, x01.y);
  *(float4*)&Xs[i0 + 8][c2] = make_float4(x10.x, x10.y, x11.x, x11.y);
  __syncthreads();

  // phase 2: Ls[i][o] = sum_c Xs[i][c] * bf16q(k_re[c,o,i,j])
  {
    int o = tid & 63;
    int ii0 = tid >> 6;            // i = ii0 + 4q
    float2 acc[4];
    const float* kr[4];
#pragma unroll
    for (int qq = 0; qq < 4; ++qq) {
      acc[qq] = make_float2(0.f, 0.f);
      if (USEKT)
        kr[qq] = ksrc + (size_t)(((ii0 + 4 * qq) * 16 + j)) * 4096 + o;
      else
        kr[qq] = ksrc + (size_t)koff + o * 256 + (ii0 + 4 * qq) * 16 + j;
    }
    for (int c = 0; c < 64; ++c) {
#pragma unroll
      for (int qq = 0; qq < 4; ++qq) {
        float2 x = Xs[ii0 + 4 * qq][c];
        float kv = USEKT ? qbf(kr[qq][c * 64])
                         : qbf(kr[qq][(size_t)c * 16384]);
        acc[qq].x = fmaf(x.x, kv, acc[qq].x);
        acc[qq].y = fmaf(x.y, kv, acc[qq].y);
      }
    }
#pragma unroll
    for (int qq = 0; qq < 4; ++qq) Ls[ii0 + 4 * qq][tid & 63] = acc[qq];
  }
  __syncthreads();

  // phase 3: Gw[a][o] = scale * sum_i Ls[i][o] e^{+2pi i a i/128}
  {
    int o = tid & 63;
    int a0 = tid >> 6;
    float lr[16], li[16];
#pragma unroll
    for (int i = 0; i < 16; ++i) { float2 l = Ls[i][o]; lr[i] = l.x; li[i] = l.y; }
    float scale = (j == 0 ? 1.0f : 2.0f) * (1.0f / 16384.0f);
#pragma unroll 4
    for (int k = 0; k < 32; ++k) {
      int a = a0 + 4 * k;
      float gr = 0.f, gi = 0.f;
#pragma unroll
      for (int i = 0; i < 16; ++i) {
        float2 t = tw[(a * i) & 127];
        gr = fmaf(lr[i], t.x, fmaf(-li[i], t.y, gr));
        gi = fmaf(lr[i], t.y, fmaf( li[i], t.x, gi));
      }
      FwGw[((size_t)(b * HH + a) * KMM + j) * CCH + o] = make_float2(gr * scale, gi * scale);
    }
  }
}

// ------ W-inverse + 1x1 conv + bias + GELU (in place) + fused next-stage W-DFT
template<int DOFWD>
__global__ __launch_bounds__(256) void k_invW_fwd(const float2* __restrict__ Gw,
                                                  const float* __restrict__ cw,
                                                  const float* __restrict__ cbv,
                                                  float* __restrict__ h,
                                                  float2* __restrict__ Fw) {
  __shared__ float hs[HH * 65];    // padded [w][c]
  __shared__ float cws[CCH * CCH];
  __shared__ float cbs[CCH];
  __shared__ float2 gs[KMM * CCH];
  __shared__ float2 tw[128];
  int tid = threadIdx.x;
  int row = blockIdx.x;
  if (tid < 128) {
    float s, c;
    sincosf(TWO_PI_128 * (float)tid, &s, &c);
    tw[tid] = make_float2(c, s);
  }
  {
    const float4* hsrc = (const float4*)(h + (size_t)row * (WWD * CCH));
#pragma unroll
    for (int k = 0; k < 8; ++k) {
      int f = tid + 256 * k;
      float4 v = hsrc[f];
      int w = f >> 4, c4 = (f & 15) * 4;
      hs[w * 65 + c4 + 0] = v.x; hs[w * 65 + c4 + 1] = v.y;
      hs[w * 65 + c4 + 2] = v.z; hs[w * 65 + c4 + 3] = v.w;
    }
    const float4* csrc = (const float4*)cw;
    float4* cdst = (float4*)cws;
#pragma unroll
    for (int k = 0; k < 4; ++k) {
      float4 v = csrc[tid + 256 * k];
      v.x = qbf(v.x); v.y = qbf(v.y); v.z = qbf(v.z); v.w = qbf(v.w);
      cdst[tid + 256 * k] = v;
    }
    if (tid < 64) cbs[tid] = qbf(cbv[tid]);
    const float4* gsrc = (const float4*)(Gw + (size_t)row * (KMM * CCH));
    float4* gdst = (float4*)gs;
    gdst[tid] = gsrc[tid];
    gdst[tid + 256] = gsrc[tid + 256];
  }
  __syncthreads();

  int og = tid & 15, o4 = og * 4;
  int w0 = tid >> 4;
  float acc[8][4];
#pragma unroll
  for (int k = 0; k < 8; ++k)
#pragma unroll
    for (int qq = 0; qq < 4; ++qq) acc[k][qq] = 0.f;

#pragma unroll 4
  for (int jj = 0; jj < 16; ++jj) {
    float4 g01 = *(float4*)&gs[jj * CCH + o4];
    float4 g23 = *(float4*)&gs[jj * CCH + o4 + 2];
#pragma unroll
    for (int k = 0; k < 8; ++k) {
      int w = w0 + 16 * k;
      float2 t = tw[(w * jj) & 127];
      acc[k][0] = fmaf(g01.x, t.x, fmaf(-g01.y, t.y, acc[k][0]));
      acc[k][1] = fmaf(g01.z, t.x, fmaf(-g01.w, t.y, acc[k][1]));
      acc[k][2] = fmaf(g23.x, t.x, fmaf(-g23.y, t.y, acc[k][2]));
      acc[k][3] = fmaf(g23.z, t.x, fmaf(-g23.w, t.y, acc[k][3]));
    }
  }
  for (int c = 0; c < 64; ++c) {
    float4 wv = *(float4*)&cws[c * 64 + o4];
#pragma unroll
    for (int k = 0; k < 8; ++k) {
      float hv = hs[(w0 + 16 * k) * 65 + c];
      acc[k][0] = fmaf(hv, wv.x, acc[k][0]);
      acc[k][1] = fmaf(hv, wv.y, acc[k][1]);
      acc[k][2] = fmaf(hv, wv.z, acc[k][2]);
      acc[k][3] = fmaf(hv, wv.w, acc[k][3]);
    }
  }
  float b0 = cbs[o4 + 0], b1 = cbs[o4 + 1], b2 = cbs[o4 + 2], b3 = cbs[o4 + 3];
#pragma unroll
  for (int k = 0; k < 8; ++k) {
    int w = w0 + 16 * k;
    acc[k][0] = gelu_f(acc[k][0] + b0);
    acc[k][1] = gelu_f(acc[k][1] + b1);
    acc[k][2] = gelu_f(acc[k][2] + b2);
    acc[k][3] = gelu_f(acc[k][3] + b3);
    float4 r = make_float4(acc[k][0], acc[k][1], acc[k][2], acc[k][3]);
    *(float4*)&h[(size_t)row * (WWD * CCH) + w * CCH + o4] = r;
  }

  if (DOFWD) {
    __syncthreads();             // all conv reads of hs complete
#pragma unroll
    for (int k = 0; k < 8; ++k) {
      int w = w0 + 16 * k;
      hs[w * 65 + o4 + 0] = acc[k][0];
      hs[w * 65 + o4 + 1] = acc[k][1];
      hs[w * 65 + o4 + 2] = acc[k][2];
      hs[w * 65 + o4 + 3] = acc[k][3];
    }
    __syncthreads();
    // fwdW for next stage: identical math to R24 k_fwdW (padded addressing)
    int cb = tid & 15;
    int j  = tid >> 4;
    float2 a0 = {0.f, 0.f}, a1 = {0.f, 0.f}, a2 = {0.f, 0.f}, a3 = {0.f, 0.f};
    for (int w = 0; w < 128; ++w) {
      const float* hp = &hs[w * 65 + cb * 4];
      float hx = hp[0], hy = hp[1], hz = hp[2], hw = hp[3];
      float2 t = tw[(w * j) & 127];
      a0.x = fmaf(hx, t.x, a0.x); a0.y = fmaf(-hx, t.y, a0.y);
      a1.x = fmaf(hy, t.x, a1.x); a1.y = fmaf(-hy, t.y, a1.y);
      a2.x = fmaf(hz, t.x, a2.x); a2.y = fmaf(-hz, t.y, a2.y);
      a3.x = fmaf(hw, t.x, a3.x); a3.y = fmaf(-hw, t.y, a3.y);
    }
    float2* outp = Fw + (size_t)row * (KMM * CCH) + j * CCH + cb * 4;
    outp[0] = a0; outp[1] = a1; outp[2] = a2; outp[3] = a3;
  }
}

// ------------- projection -> bf16 pairs packed IM-FIRST (im low, re high)
__global__ __launch_bounds__(256) void k_proj(const float* __restrict__ h,
                                              const float* __restrict__ p1w,
                                              const float* __restrict__ p1b,
                                              const float* __restrict__ p2w,
                                              const float* __restrict__ p2b,
                                              u32* __restrict__ out) {
  __shared__ float hsT[CCH * WWD];
  __shared__ float p1s[CCH * 128];
  int tid = threadIdx.x;
  int row = blockIdx.x;
  {
    const float4* src = (const float4*)(h + (size_t)row * (WWD * CCH));
#pragma unroll
    for (int k = 0; k < 8; ++k) {
      int f = tid + 256 * k;
      float4 v = src[f];
      int w = f >> 4, c4 = (f & 15) * 4;
      hsT[(c4 + 0) * 128 + w] = v.x; hsT[(c4 + 1) * 128 + w] = v.y;
      hsT[(c4 + 2) * 128 + w] = v.z; hsT[(c4 + 3) * 128 + w] = v.w;
    }
    const float4* ps = (const float4*)p1w;
    float4* pd = (float4*)p1s;
#pragma unroll
    for (int k = 0; k < 8; ++k) {
      float4 v = ps[tid + 256 * k];
      v.x = qbf(v.x); v.y = qbf(v.y); v.z = qbf(v.z); v.w = qbf(v.w);
      pd[tid + 256 * k] = v;
    }
  }
  __syncthreads();

  int wt = tid >> 4;
  int jt = tid & 15;
  float acc[8][8];
#pragma unroll
  for (int a = 0; a < 8; ++a)
#pragma unroll
    for (int bq = 0; bq < 8; ++bq) acc[a][bq] = 0.f;

  for (int c = 0; c < 64; ++c) {
    float4 ha = *(float4*)&hsT[c * 128 + wt * 8];
    float4 hb = *(float4*)&hsT[c * 128 + wt * 8 + 4];
    float4 pa = *(float4*)&p1s[c * 128 + jt * 8];
    float4 pb = *(float4*)&p1s[c * 128 + jt * 8 + 4];
    float hv[8] = {ha.x, ha.y, ha.z, ha.w, hb.x, hb.y, hb.z, hb.w};
    float pv[8] = {pa.x, pa.y, pa.z, pa.w, pb.x, pb.y, pb.z, pb.w};
#pragma unroll
    for (int a = 0; a < 8; ++a)
#pragma unroll
      for (int bq = 0; bq < 8; ++bq) acc[a][bq] = fmaf(hv[a], pv[bq], acc[a][bq]);
  }

  float o0[8], o1[8];
#pragma unroll
  for (int a = 0; a < 8; ++a) { o0[a] = 0.f; o1[a] = 0.f; }
#pragma unroll
  for (int jj = 0; jj < 8; ++jj) {
    int jdx = jt * 8 + jj;
    float bb = qbf(p1b[jdx]);
    float w20 = qbf(p2w[jdx * 2 + 0]), w21 = qbf(p2w[jdx * 2 + 1]);
#pragma unroll
    for (int a = 0; a < 8; ++a) {
      float g = gelu_f(acc[a][jj] + bb);
      o0[a] = fmaf(g, w20, o0[a]);
      o1[a] = fmaf(g, w21, o1[a]);
    }
  }
#pragma unroll
  for (int m = 1; m < 16; m <<= 1) {
#pragma unroll
    for (int a = 0; a < 8; ++a) {
      o0[a] += __shfl_xor(o0[a], m);
      o1[a] += __shfl_xor(o1[a], m);
    }
  }
  if (jt == 0) {
    float bb0 = qbf(p2b[0]), bb1 = qbf(p2b[1]);
#pragma unroll
    for (int a = 0; a < 8; ++a) {
      int w = wt * 8 + a;
      out[(size_t)row * 128 + w] =
          (u32)f2bf(o1[a] + bb1) | ((u32)f2bf(o0[a] + bb0) << 16);
    }
  }
}

// ----------------------------------------------------------------------------
extern "C" void kernel_launch(void* const* d_in, const int* in_sizes, int n_in,
                              void* d_out, int out_size, void* d_ws, size_t ws_size,
                              hipStream_t stream) {
  const float4* x     = (const float4*)d_in[0];
  const float*  lw    = (const float*)d_in[1];
  const float*  lb    = (const float*)d_in[2];
  const float*  kerns = (const float*)d_in[3];   // f32 REAL parts, 24MB
  const float*  convw = (const float*)d_in[4];
  const float*  convb = (const float*)d_in[5];
  const float*  p1w   = (const float*)d_in[6];
  const float*  p1b   = (const float*)d_in[7];
  const float*  p2w   = (const float*)d_in[8];
  const float*  p2b   = (const float*)d_in[9];

  // ws: h = CH*4MiB, Fw = CH*1MiB, Kt (optional) = 4MiB
  int CH; bool useKt;
  if      (ws_size >= 46137344u) { CH = 8; useKt = true;  }   // 44 MiB
  else if (ws_size >= 41943040u) { CH = 8; useKt = false; }   // 40 MiB (R24 path)
  else if (ws_size >= 20971520u) { CH = 4; useKt = false; }
  else if (ws_size >= 10485760u) { CH = 2; useKt = false; }
  else if (ws_size >=  5242880u) { CH = 1; useKt = false; }
  else {
    k_sentinel<<<512, 256, 0, stream>>>((u32*)d_out, 12345.0f);
    return;
  }
  size_t hFloats  = (size_t)CH * HH * WWD * CCH;      // CH * 1,048,576
  size_t fwFloats = (size_t)CH * HH * KMM * CCH * 2;  // CH *   262,144
  float*  h  = (float*)d_ws;
  float2* Fw = (float2*)((float*)d_ws + hFloats);
  float*  Kt = (float*)d_ws + hFloats + fwFloats;     // 4 MiB when useKt

  for (int b0 = 0; b0 < 8; b0 += CH) {
    k_lift_fwd<<<CH * HH, 256, 0, stream>>>(x, lw, lb, h, Fw, b0 * HH);

    for (int s = 0; s < NSTG; ++s) {
      if (useKt) {
        k_ktrans<<<dim3(8, 128), dim3(32, 8), 0, stream>>>(
            kerns + (size_t)s * 1048576, Kt);
        k_modes<1><<<CH * KMM, 256, 0, stream>>>(Fw, Kt, 0);
      } else {
        k_modes<0><<<CH * KMM, 256, 0, stream>>>(Fw, kerns, s * 1048576);
      }
      if (s < NSTG - 1)
        k_invW_fwd<1><<<CH * HH, 256, 0, stream>>>(Fw, convw + s * 4096,
                                                   convb + s * 64, h, Fw);
      else
        k_invW_fwd<0><<<CH * HH, 256, 0, stream>>>(Fw, convw + s * 4096,
                                                   convb + s * 64, h, Fw);
    }

    k_proj<<<CH * HH, 256, 0, stream>>>(h, p1w, p1b, p2w, p2b,
                                        (u32*)d_out + (size_t)b0 * (HH * WWD));
  }
}

// Round 26
// 577.206 us; speedup vs baseline: 1.3346x; 1.0046x over previous
//
#include <hip/hip_runtime.h>
#include <math.h>

// FNO: B=8, H=W=128, C=64, KMAX=16, STAGES=6, PROJ_HIDDEN=128
// PASSING MODEL (R24/R25, absmax 0.004394531): kernels = f32 REAL parts (24MB),
// inputs f32 quantized through bf16 on load, output bf16 pairs IM-FIRST.
// R26 changes (bit-identical math, layout only):
//   - k_invW_fwd: w = w0*8+k lane mapping (bank conflicts 8-way -> 4-way)
//   - k_invW_fwd: conv weights stored in LDS as u16 bf16 codes (LDS 59->51KB,
//     3 blocks/CU instead of 2)

#define HH    128
#define WWD   128
#define CCH   64
#define KMM   16
#define NSTG  6

#define TWO_PI_128 0.04908738521234052f   // 2*pi/128

typedef unsigned int  u32;
typedef unsigned short u16;

__device__ __forceinline__ float bf2f(u16 u) {
  union { u32 i; float f; } v; v.i = ((u32)u) << 16; return v.f;
}
__device__ __forceinline__ u16 f2bf(float f) {
  union { float f; u32 i; } v; v.f = f;
  u32 r = v.i + 0x7FFFu + ((v.i >> 16) & 1u);   // RNE
  return (u16)(r >> 16);
}
__device__ __forceinline__ float qbf(float f) { return bf2f(f2bf(f)); }

__device__ __forceinline__ float gelu_f(float x) {
  const float k0 = 0.7978845608028654f;   // sqrt(2/pi)
  float t = tanhf(k0 * (x + 0.044715f * x * x * x));
  return 0.5f * x * (1.0f + t);
}

// -------------------------------------------------------- ws sentinel
__global__ __launch_bounds__(256) void k_sentinel(u32* __restrict__ out, float v) {
  int gid = blockIdx.x * 256 + threadIdx.x;
  u16 b = f2bf(v);
  out[gid] = (u32)b | ((u32)b << 16);
}

// ------------------------------------------- fused lift + W-DFT (per row)
__global__ __launch_bounds__(256) void k_lift_fwd(const float4* __restrict__ x,
                                                  const float* __restrict__ lw,
                                                  const float* __restrict__ lb,
                                                  float* __restrict__ h,
                                                  float2* __restrict__ Fw,
                                                  int rowBase) {
  __shared__ float hs[HH * CCH];   // [w][c] unpadded, 32KB
  __shared__ float4 xs[128];
  __shared__ float lwf[256];
  __shared__ float lbf[64];
  __shared__ float2 tw[128];
  int tid = threadIdx.x;
  int row = blockIdx.x;            // chunk-local row
  lwf[tid] = qbf(lw[tid]);
  if (tid < 64) lbf[tid] = qbf(lb[tid]);
  if (tid < 128) {
    float s, c;
    sincosf(TWO_PI_128 * (float)tid, &s, &c);
    tw[tid] = make_float2(c, s);
    float4 xv = x[(size_t)(rowBase + row) * 128 + tid];
    xs[tid] = make_float4(qbf(xv.x), qbf(xv.y), qbf(xv.z), qbf(xv.w));
  }
  __syncthreads();
#pragma unroll
  for (int k = 0; k < 32; ++k) {
    int e = tid + 256 * k;         // 0..8191
    int w = e >> 6, c = e & 63;
    float4 xv = xs[w];
    float acc = lbf[c];
    acc = fmaf(xv.x, lwf[c], acc);
    acc = fmaf(xv.y, lwf[64 + c], acc);
    acc = fmaf(xv.z, lwf[128 + c], acc);
    acc = fmaf(xv.w, lwf[192 + c], acc);
    hs[e] = acc;
  }
  __syncthreads();
  {
    float4* dst = (float4*)(h + (size_t)row * 8192);
    const float4* s4 = (const float4*)hs;
#pragma unroll
    for (int k = 0; k < 8; ++k) dst[tid + 256 * k] = s4[tid + 256 * k];
  }
  int cb = tid & 15;
  int j  = tid >> 4;
  float2 acc0 = {0.f, 0.f}, acc1 = {0.f, 0.f}, acc2 = {0.f, 0.f}, acc3 = {0.f, 0.f};
  for (int w = 0; w < 128; ++w) {
    float4 hv = *(const float4*)&hs[w * CCH + cb * 4];
    float2 t = tw[(w * j) & 127];
    acc0.x = fmaf(hv.x, t.x, acc0.x); acc0.y = fmaf(-hv.x, t.y, acc0.y);
    acc1.x = fmaf(hv.y, t.x, acc1.x); acc1.y = fmaf(-hv.y, t.y, acc1.y);
    acc2.x = fmaf(hv.z, t.x, acc2.x); acc2.y = fmaf(-hv.z, t.y, acc2.y);
    acc3.x = fmaf(hv.w, t.x, acc3.x); acc3.y = fmaf(-hv.w, t.y, acc3.y);
  }
  float2* outp = Fw + (size_t)row * (KMM * CCH) + j * CCH + cb * 4;
  outp[0] = acc0; outp[1] = acc1; outp[2] = acc2; outp[3] = acc3;
}

// ------------------------------------------------- per-stage kernel transpose
__global__ void k_ktrans(const float* __restrict__ src, float* __restrict__ dst) {
  __shared__ float t[32][33];
  int tx = threadIdx.x, ty = threadIdx.y;       // (32,8)
  int c0 = blockIdx.x * 32;                     // ij tile
  int r0 = blockIdx.y * 32;                     // co tile
#pragma unroll
  for (int k = 0; k < 4; ++k)
    t[ty + 8 * k][tx] = src[(size_t)(r0 + ty + 8 * k) * 256 + c0 + tx];
  __syncthreads();
#pragma unroll
  for (int k = 0; k < 4; ++k)
    dst[(size_t)(c0 + ty + 8 * k) * 4096 + r0 + tx] = t[tx][ty + 8 * k];
}

// --------------------------------------- fused H-DFT -> mode mix -> H-iDFT
template<int USEKT>
__global__ __launch_bounds__(256) void k_modes(float2* __restrict__ FwGw,
                                               const float* __restrict__ ksrc,
                                               int koff) {
  __shared__ float2 fs[16][CCH];
  __shared__ float2 Xs[KMM][CCH];
  __shared__ float2 Ls[KMM][CCH];
  __shared__ float2 tw[128];
  int tid = threadIdx.x;
  int b = blockIdx.x >> 4;
  int j = blockIdx.x & 15;
  if (tid < 128) {
    float s, c;
    sincosf(TWO_PI_128 * (float)tid, &s, &c);
    tw[tid] = make_float2(c, s);
  }

  int c2 = (tid & 31) * 2;
  int i0 = tid >> 5;
  int seg = tid >> 5, q = tid & 31;
  float2 x00 = {0,0}, x01 = {0,0}, x10 = {0,0}, x11 = {0,0};
  for (int ck = 0; ck < 8; ++ck) {
    __syncthreads();
#pragma unroll
    for (int p = 0; p < 2; ++p) {
      int a = ck * 16 + p * 8 + seg;
      ((float4*)&fs[p * 8 + seg][0])[q] =
          ((const float4*)(FwGw + ((size_t)(b * HH + a) * KMM + j) * CCH))[q];
    }
    __syncthreads();
#pragma unroll
    for (int aa = 0; aa < 16; ++aa) {
      int a = ck * 16 + aa;
      float4 f = *(float4*)&fs[aa][c2];
      float2 t0 = tw[(a * i0) & 127];
      float2 t1 = tw[(a * (i0 + 8)) & 127];
      x00.x = fmaf(f.x, t0.x, fmaf( f.y, t0.y, x00.x));
      x00.y = fmaf(f.y, t0.x, fmaf(-f.x, t0.y, x00.y));
      x01.x = fmaf(f.z, t0.x, fmaf( f.w, t0.y, x01.x));
      x01.y = fmaf(f.w, t0.x, fmaf(-f.z, t0.y, x01.y));
      x10.x = fmaf(f.x, t1.x, fmaf( f.y, t1.y, x10.x));
      x10.y = fmaf(f.y, t1.x, fmaf(-f.x, t1.y, x10.y));
      x11.x = fmaf(f.z, t1.x, fmaf( f.w, t1.y, x11.x));
      x11.y = fmaf(f.w, t1.x, fmaf(-f.z, t1.y, x11.y));
    }
  }
  *(float4*)&Xs[i0][c2]     = make_float4(x00.x, x00.y, x01.x, x01.y);
  *(float4*)&Xs[i0 + 8][c2] = make_float4(x10.x, x10.y, x11.x, x11.y);
  __syncthreads();

  {
    int o = tid & 63;
    int ii0 = tid >> 6;
    float2 acc[4];
    const float* kr[4];
#pragma unroll
    for (int qq = 0; qq < 4; ++qq) {
      acc[qq] = make_float2(0.f, 0.f);
      if (USEKT)
        kr[qq] = ksrc + (size_t)(((ii0 + 4 * qq) * 16 + j)) * 4096 + o;
      else
        kr[qq] = ksrc + (size_t)koff + o * 256 + (ii0 + 4 * qq) * 16 + j;
    }
    for (int c = 0; c < 64; ++c) {
#pragma unroll
      for (int qq = 0; qq < 4; ++qq) {
        float2 x = Xs[ii0 + 4 * qq][c];
        float kv = USEKT ? qbf(kr[qq][c * 64])
                         : qbf(kr[qq][(size_t)c * 16384]);
        acc[qq].x = fmaf(x.x, kv, acc[qq].x);
        acc[qq].y = fmaf(x.y, kv, acc[qq].y);
      }
    }
#pragma unroll
    for (int qq = 0; qq < 4; ++qq) Ls[ii0 + 4 * qq][tid & 63] = acc[qq];
  }
  __syncthreads();

  {
    int o = tid & 63;
    int a0 = tid >> 6;
    float lr[16], li[16];
#pragma unroll
    for (int i = 0; i < 16; ++i) { float2 l = Ls[i][o]; lr[i] = l.x; li[i] = l.y; }
    float scale = (j == 0 ? 1.0f : 2.0f) * (1.0f / 16384.0f);
#pragma unroll 4
    for (int k = 0; k < 32; ++k) {
      int a = a0 + 4 * k;
      float gr = 0.f, gi = 0.f;
#pragma unroll
      for (int i = 0; i < 16; ++i) {
        float2 t = tw[(a * i) & 127];
        gr = fmaf(lr[i], t.x, fmaf(-li[i], t.y, gr));
        gi = fmaf(lr[i], t.y, fmaf( li[i], t.x, gi));
      }
      FwGw[((size_t)(b * HH + a) * KMM + j) * CCH + o] = make_float2(gr * scale, gi * scale);
    }
  }
}

// ------ W-inverse + 1x1 conv + bias + GELU (in place) + fused next-stage W-DFT
// Lane mapping: w = w0*8 + k  (k<8) — halves LDS bank conflicts vs w0+16k.
// Per-output accumulation order (jj then c) identical to R24/R25.
template<int DOFWD>
__global__ __launch_bounds__(256) void k_invW_fwd(const float2* __restrict__ Gw,
                                                  const float* __restrict__ cw,
                                                  const float* __restrict__ cbv,
                                                  float* __restrict__ h,
                                                  float2* __restrict__ Fw) {
  __shared__ float hs[HH * 65];    // padded [w][c] 33,280B
  __shared__ u16 cws[CCH * CCH];   // bf16 codes, 8,192B
  __shared__ float cbs[CCH];
  __shared__ float2 gs[KMM * CCH]; // 8,192B
  __shared__ float2 tw[128];
  int tid = threadIdx.x;
  int row = blockIdx.x;
  if (tid < 128) {
    float s, c;
    sincosf(TWO_PI_128 * (float)tid, &s, &c);
    tw[tid] = make_float2(c, s);
  }
  {
    const float4* hsrc = (const float4*)(h + (size_t)row * (WWD * CCH));
#pragma unroll
    for (int k = 0; k < 8; ++k) {
      int f = tid + 256 * k;
      float4 v = hsrc[f];
      int w = f >> 4, c4 = (f & 15) * 4;
      hs[w * 65 + c4 + 0] = v.x; hs[w * 65 + c4 + 1] = v.y;
      hs[w * 65 + c4 + 2] = v.z; hs[w * 65 + c4 + 3] = v.w;
    }
    const float4* csrc = (const float4*)cw;
#pragma unroll
    for (int k = 0; k < 4; ++k) {
      float4 v = csrc[tid + 256 * k];
      int e = (tid + 256 * k) * 4;
      cws[e + 0] = f2bf(v.x); cws[e + 1] = f2bf(v.y);
      cws[e + 2] = f2bf(v.z); cws[e + 3] = f2bf(v.w);
    }
    if (tid < 64) cbs[tid] = qbf(cbv[tid]);
    const float4* gsrc = (const float4*)(Gw + (size_t)row * (KMM * CCH));
    float4* gdst = (float4*)gs;
    gdst[tid] = gsrc[tid];
    gdst[tid + 256] = gsrc[tid + 256];
  }
  __syncthreads();

  int og = tid & 15, o4 = og * 4;
  int w0 = tid >> 4;               // w = w0*8 + k, k<8
  float acc[8][4];
#pragma unroll
  for (int k = 0; k < 8; ++k)
#pragma unroll
    for (int qq = 0; qq < 4; ++qq) acc[k][qq] = 0.f;

  // spectral inverse along W (jj order identical)
#pragma unroll 4
  for (int jj = 0; jj < 16; ++jj) {
    float4 g01 = *(float4*)&gs[jj * CCH + o4];
    float4 g23 = *(float4*)&gs[jj * CCH + o4 + 2];
#pragma unroll
    for (int k = 0; k < 8; ++k) {
      int w = w0 * 8 + k;
      float2 t = tw[(w * jj) & 127];
      acc[k][0] = fmaf(g01.x, t.x, fmaf(-g01.y, t.y, acc[k][0]));
      acc[k][1] = fmaf(g01.z, t.x, fmaf(-g01.w, t.y, acc[k][1]));
      acc[k][2] = fmaf(g23.x, t.x, fmaf(-g23.y, t.y, acc[k][2]));
      acc[k][3] = fmaf(g23.z, t.x, fmaf(-g23.w, t.y, acc[k][3]));
    }
  }
  // 1x1 conv (c order identical; weights decoded from bf16 codes = same values)
  for (int c = 0; c < 64; ++c) {
    const u16* wp = &cws[c * 64 + o4];
    float w0v = bf2f(wp[0]), w1v = bf2f(wp[1]);
    float w2v = bf2f(wp[2]), w3v = bf2f(wp[3]);
#pragma unroll
    for (int k = 0; k < 8; ++k) {
      float hv = hs[(w0 * 8 + k) * 65 + c];
      acc[k][0] = fmaf(hv, w0v, acc[k][0]);
      acc[k][1] = fmaf(hv, w1v, acc[k][1]);
      acc[k][2] = fmaf(hv, w2v, acc[k][2]);
      acc[k][3] = fmaf(hv, w3v, acc[k][3]);
    }
  }
  float b0 = cbs[o4 + 0], b1 = cbs[o4 + 1], b2 = cbs[o4 + 2], b3 = cbs[o4 + 3];
#pragma unroll
  for (int k = 0; k < 8; ++k) {
    int w = w0 * 8 + k;
    acc[k][0] = gelu_f(acc[k][0] + b0);
    acc[k][1] = gelu_f(acc[k][1] + b1);
    acc[k][2] = gelu_f(acc[k][2] + b2);
    acc[k][3] = gelu_f(acc[k][3] + b3);
    float4 r = make_float4(acc[k][0], acc[k][1], acc[k][2], acc[k][3]);
    *(float4*)&h[(size_t)row * (WWD * CCH) + w * CCH + o4] = r;
  }

  if (DOFWD) {
    __syncthreads();             // all conv reads of hs complete
#pragma unroll
    for (int k = 0; k < 8; ++k) {
      int w = w0 * 8 + k;
      hs[w * 65 + o4 + 0] = acc[k][0];
      hs[w * 65 + o4 + 1] = acc[k][1];
      hs[w * 65 + o4 + 2] = acc[k][2];
      hs[w * 65 + o4 + 3] = acc[k][3];
    }
    __syncthreads();
    int cb = tid & 15;
    int j  = tid >> 4;
    float2 a0 = {0.f, 0.f}, a1 = {0.f, 0.f}, a2 = {0.f, 0.f}, a3 = {0.f, 0.f};
    for (int w = 0; w < 128; ++w) {
      const float* hp = &hs[w * 65 + cb * 4];
      float hx = hp[0], hy = hp[1], hz = hp[2], hw = hp[3];
      float2 t = tw[(w * j) & 127];
      a0.x = fmaf(hx, t.x, a0.x); a0.y = fmaf(-hx, t.y, a0.y);
      a1.x = fmaf(hy, t.x, a1.x); a1.y = fmaf(-hy, t.y, a1.y);
      a2.x = fmaf(hz, t.x, a2.x); a2.y = fmaf(-hz, t.y, a2.y);
      a3.x = fmaf(hw, t.x, a3.x); a3.y = fmaf(-hw, t.y, a3.y);
    }
    float2* outp = Fw + (size_t)row * (KMM * CCH) + j * CCH + cb * 4;
    outp[0] = a0; outp[1] = a1; outp[2] = a2; outp[3] = a3;
  }
}

// ------------- projection -> bf16 pairs packed IM-FIRST (im low, re high)
__global__ __launch_bounds__(256) void k_proj(const float* __restrict__ h,
                                              const float* __restrict__ p1w,
                                              const float* __restrict__ p1b,
                                              const float* __restrict__ p2w,
                                              const float* __restrict__ p2b,
                                              u32* __restrict__ out) {
  __shared__ float hsT[CCH * WWD];
  __shared__ float p1s[CCH * 128];
  int tid = threadIdx.x;
  int row = blockIdx.x;
  {
    const float4* src = (const float4*)(h + (size_t)row * (WWD * CCH));
#pragma unroll
    for (int k = 0; k < 8; ++k) {
      int f = tid + 256 * k;
      float4 v = src[f];
      int w = f >> 4, c4 = (f & 15) * 4;
      hsT[(c4 + 0) * 128 + w] = v.x; hsT[(c4 + 1) * 128 + w] = v.y;
      hsT[(c4 + 2) * 128 + w] = v.z; hsT[(c4 + 3) * 128 + w] = v.w;
    }
    const float4* ps = (const float4*)p1w;
    float4* pd = (float4*)p1s;
#pragma unroll
    for (int k = 0; k < 8; ++k) {
      float4 v = ps[tid + 256 * k];
      v.x = qbf(v.x); v.y = qbf(v.y); v.z = qbf(v.z); v.w = qbf(v.w);
      pd[tid + 256 * k] = v;
    }
  }
  __syncthreads();

  int wt = tid >> 4;
  int jt = tid & 15;
  float acc[8][8];
#pragma unroll
  for (int a = 0; a < 8; ++a)
#pragma unroll
    for (int bq = 0; bq < 8; ++bq) acc[a][bq] = 0.f;

  for (int c = 0; c < 64; ++c) {
    float4 ha = *(float4*)&hsT[c * 128 + wt * 8];
    float4 hb = *(float4*)&hsT[c * 128 + wt * 8 + 4];
    float4 pa = *(float4*)&p1s[c * 128 + jt * 8];
    float4 pb = *(float4*)&p1s[c * 128 + jt * 8 + 4];
    float hv[8] = {ha.x, ha.y, ha.z, ha.w, hb.x, hb.y, hb.z, hb.w};
    float pv[8] = {pa.x, pa.y, pa.z, pa.w, pb.x, pb.y, pb.z, pb.w};
#pragma unroll
    for (int a = 0; a < 8; ++a)
#pragma unroll
      for (int bq = 0; bq < 8; ++bq) acc[a][bq] = fmaf(hv[a], pv[bq], acc[a][bq]);
  }

  float o0[8], o1[8];
#pragma unroll
  for (int a = 0; a < 8; ++a) { o0[a] = 0.f; o1[a] = 0.f; }
#pragma unroll
  for (int jj = 0; jj < 8; ++jj) {
    int jdx = jt * 8 + jj;
    float bb = qbf(p1b[jdx]);
    float w20 = qbf(p2w[jdx * 2 + 0]), w21 = qbf(p2w[jdx * 2 + 1]);
#pragma unroll
    for (int a = 0; a < 8; ++a) {
      float g = gelu_f(acc[a][jj] + bb);
      o0[a] = fmaf(g, w20, o0[a]);
      o1[a] = fmaf(g, w21, o1[a]);
    }
  }
#pragma unroll
  for (int m = 1; m < 16; m <<= 1) {
#pragma unroll
    for (int a = 0; a < 8; ++a) {
      o0[a] += __shfl_xor(o0[a], m);
      o1[a] += __shfl_xor(o1[a], m);
    }
  }
  if (jt == 0) {
    float bb0 = qbf(p2b[0]), bb1 = qbf(p2b[1]);
#pragma unroll
    for (int a = 0; a < 8; ++a) {
      int w = wt * 8 + a;
      out[(size_t)row * 128 + w] =
          (u32)f2bf(o1[a] + bb1) | ((u32)f2bf(o0[a] + bb0) << 16);
    }
  }
}

// ----------------------------------------------------------------------------
extern "C" void kernel_launch(void* const* d_in, const int* in_sizes, int n_in,
                              void* d_out, int out_size, void* d_ws, size_t ws_size,
                              hipStream_t stream) {
  const float4* x     = (const float4*)d_in[0];
  const float*  lw    = (const float*)d_in[1];
  const float*  lb    = (const float*)d_in[2];
  const float*  kerns = (const float*)d_in[3];   // f32 REAL parts, 24MB
  const float*  convw = (const float*)d_in[4];
  const float*  convb = (const float*)d_in[5];
  const float*  p1w   = (const float*)d_in[6];
  const float*  p1b   = (const float*)d_in[7];
  const float*  p2w   = (const float*)d_in[8];
  const float*  p2b   = (const float*)d_in[9];

  // ws: h = CH*4MiB, Fw = CH*1MiB, Kt (optional) = 4MiB
  int CH; bool useKt;
  if      (ws_size >= 46137344u) { CH = 8; useKt = true;  }   // 44 MiB
  else if (ws_size >= 41943040u) { CH = 8; useKt = false; }   // 40 MiB
  else if (ws_size >= 20971520u) { CH = 4; useKt = false; }
  else if (ws_size >= 10485760u) { CH = 2; useKt = false; }
  else if (ws_size >=  5242880u) { CH = 1; useKt = false; }
  else {
    k_sentinel<<<512, 256, 0, stream>>>((u32*)d_out, 12345.0f);
    return;
  }
  size_t hFloats  = (size_t)CH * HH * WWD * CCH;
  size_t fwFloats = (size_t)CH * HH * KMM * CCH * 2;
  float*  h  = (float*)d_ws;
  float2* Fw = (float2*)((float*)d_ws + hFloats);
  float*  Kt = (float*)d_ws + hFloats + fwFloats;

  for (int b0 = 0; b0 < 8; b0 += CH) {
    k_lift_fwd<<<CH * HH, 256, 0, stream>>>(x, lw, lb, h, Fw, b0 * HH);

    for (int s = 0; s < NSTG; ++s) {
      if (useKt) {
        k_ktrans<<<dim3(8, 128), dim3(32, 8), 0, stream>>>(
            kerns + (size_t)s * 1048576, Kt);
        k_modes<1><<<CH * KMM, 256, 0, stream>>>(Fw, Kt, 0);
      } else {
        k_modes<0><<<CH * KMM, 256, 0, stream>>>(Fw, kerns, s * 1048576);
      }
      if (s < NSTG - 1)
        k_invW_fwd<1><<<CH * HH, 256, 0, stream>>>(Fw, convw + s * 4096,
                                                   convb + s * 64, h, Fw);
      else
        k_invW_fwd<0><<<CH * HH, 256, 0, stream>>>(Fw, convw + s * 4096,
                                                   convb + s * 64, h, Fw);
    }

    k_proj<<<CH * HH, 256, 0, stream>>>(h, p1w, p1b, p2w, p2b,
                                        (u32*)d_out + (size_t)b0 * (HH * WWD));
  }
}